// Round 11
// baseline (7036.464 us; speedup 1.0000x reference)
//
#include <hip/hip_runtime.h>
#include <cmath>

#define HH   128
#define G3   384
#define TT   512
#define BTOT 512
#define WT   16                // tokens per windowed x-GEMM
#define NBLK BTOT              // 512 blocks, 1 row each -> 2 blocks/CU
#define NTHR 512               // 8 waves; launch_bounds caps VGPR at 128

__device__ __forceinline__ float sigmoidf_(float x) {
    return 1.0f / (1.0f + __expf(-x));
}
__device__ __forceinline__ float tanhf_(float x) {
    float e = __expf(2.0f * x);
    return 1.0f - 2.0f / (e + 1.0f);
}
// lgkmcnt(0)-only barrier: LDS writes visible; vmem stores/loads stay in flight
__device__ __forceinline__ void lds_barrier() {
    asm volatile("s_waitcnt lgkmcnt(0)" ::: "memory");
    __builtin_amdgcn_s_barrier();
}

// One GRU layer, ONE batch row per block (512 blocks -> 2/CU so two
// independent recurrences hide each other's per-step latency chain).
// kt=tid&3 owns a 32-wide k-slice of Whh rows {j,128+j,256+j} (j=gt=tid>>2):
// 96 weights pinned in VGPRs. x-part via windowed GEMM (WT tokens) into s_xi,
// Wih streamed from L2. h double-buffered in bank-padded LDS; 1 lgkm
// barrier/step.
template <bool FIRST, bool LAST>
__global__ __launch_bounds__(NTHR, 4) void gru_layer(
    const float* in, float* out,   // mid layers alias (in-place): NO __restrict__
    const float* __restrict__ Wih, const float* __restrict__ Whh,
    const float* __restrict__ bih, const float* __restrict__ bhh,
    const float* __restrict__ fcw, const float* __restrict__ fcb,
    float* __restrict__ fcout) {
    const int tid = threadIdx.x;
    const int kt  = tid & 3;
    const int gt  = tid >> 2;          // hidden unit j in [0,128)
    const int b   = blockIdx.x;        // one batch row per block

    // h slices padded to 36 floats: kt-slice -> bank quad 4kt (conflict-free b128)
    __shared__ __align__(16) float s_h[2][4][36];
    // FIRST: whole x row (512*5). Mid: WT staged input tokens.
    __shared__ __align__(16) float s_in[FIRST ? (TT * 5) : (WT * HH)];
    // Mid: window xi results. FIRST: dummy.
    __shared__ __align__(16) float s_xi[FIRST ? 4 : (WT * G3)];

    // ---- recurrent weights: rows {gt,128+gt,256+gt}, k-slice kt*32, pinned ----
    float wh[3][32];
#pragma unroll
    for (int i = 0; i < 3; ++i) {
        const float* wr = Whh + (size_t)(i * HH + gt) * HH + kt * 32;
#pragma unroll
        for (int j = 0; j < 32; j += 4) {
            float4 v = *(const float4*)(wr + j);
            wh[i][j] = v.x; wh[i][j + 1] = v.y; wh[i][j + 2] = v.z; wh[i][j + 3] = v.w;
        }
    }
#pragma unroll
    for (int i = 0; i < 3; ++i)
#pragma unroll
        for (int j = 0; j < 32; ++j) asm volatile("" : "+v"(wh[i][j]));

    float wx5[3][5];
    if constexpr (FIRST) {
#pragma unroll
        for (int i = 0; i < 3; ++i)
#pragma unroll
            for (int j = 0; j < 5; ++j) wx5[i][j] = Wih[(i * HH + gt) * 5 + j];
    }

    const float br  = bih[gt] + bhh[gt];
    const float bz  = bih[HH + gt] + bhh[HH + gt];
    const float bxn = bih[2 * HH + gt];
    const float bhn = bhh[2 * HH + gt];

    if (tid < HH) s_h[0][tid >> 5][tid & 31] = 0.0f;
    if constexpr (FIRST) {
        // stage the entire x row once: 2560 floats = 5 per thread, coalesced
#pragma unroll
        for (int r = 0; r < 5; ++r) {
            int idx = r * NTHR + tid;
            s_in[idx] = in[(size_t)b * TT * 5 + idx];
        }
    }
    __syncthreads();

    for (int w = 0; w < TT / WT; ++w) {
        if constexpr (!FIRST) {
            // ---- stage WT input tokens: 512 float4, one per thread ----
            {
                int tok = tid >> 5, k4 = (tid & 31) * 4;
                float4 v = *(const float4*)&in[((size_t)b * TT + w * WT + tok) * HH + k4];
                *(float4*)&s_in[tok * HH + k4] = v;
            }
            lds_barrier();

            // ---- X GEMM: xi[tok][{g,128+g,256+g}] for this window ----
            {
                const int g  = tid & 127;
                const int tq = tid >> 7;               // token quarter [0,4)
                const float* w0p = Wih + (size_t)g * HH;
                const float* w1p = Wih + (size_t)(HH + g) * HH;
                const float* w2p = Wih + (size_t)(2 * HH + g) * HH;
                float acc[3][4];
#pragma unroll
                for (int i = 0; i < 3; ++i)
#pragma unroll
                    for (int tt = 0; tt < 4; ++tt) acc[i][tt] = 0.0f;
#pragma unroll 4
                for (int kc = 0; kc < 32; ++kc) {
                    float4 wa = *(const float4*)(w0p + kc * 4);
                    float4 wb = *(const float4*)(w1p + kc * 4);
                    float4 wc = *(const float4*)(w2p + kc * 4);
#pragma unroll
                    for (int tt = 0; tt < 4; ++tt) {
                        float4 sv = *(const float4*)&s_in[(tq * 4 + tt) * HH + kc * 4];
                        acc[0][tt] = fmaf(wa.x, sv.x, acc[0][tt]);
                        acc[0][tt] = fmaf(wa.y, sv.y, acc[0][tt]);
                        acc[0][tt] = fmaf(wa.z, sv.z, acc[0][tt]);
                        acc[0][tt] = fmaf(wa.w, sv.w, acc[0][tt]);
                        acc[1][tt] = fmaf(wb.x, sv.x, acc[1][tt]);
                        acc[1][tt] = fmaf(wb.y, sv.y, acc[1][tt]);
                        acc[1][tt] = fmaf(wb.z, sv.z, acc[1][tt]);
                        acc[1][tt] = fmaf(wb.w, sv.w, acc[1][tt]);
                        acc[2][tt] = fmaf(wc.x, sv.x, acc[2][tt]);
                        acc[2][tt] = fmaf(wc.y, sv.y, acc[2][tt]);
                        acc[2][tt] = fmaf(wc.z, sv.z, acc[2][tt]);
                        acc[2][tt] = fmaf(wc.w, sv.w, acc[2][tt]);
                    }
                }
#pragma unroll
                for (int tt = 0; tt < 4; ++tt) {
                    int tok = tq * 4 + tt;
                    s_xi[tok * G3 + g]          = acc[0][tt];
                    s_xi[tok * G3 + HH + g]     = acc[1][tt];
                    s_xi[tok * G3 + 2 * HH + g] = acc[2][tt];
                }
            }
            lds_barrier();
        }

        // ================= recurrent steps for this window =================
        for (int tw = 0; tw < WT; ++tw) {
            const int t   = w * WT + tw;
            const int cur = t & 1;

            float a0 = 0.f, a1 = 0.f, a2 = 0.f;
            const float* hp = &s_h[cur][kt][0];
#pragma unroll
            for (int jj = 0; jj < 32; jj += 4) {
                float4 u = *(const float4*)(hp + jj);
                a0 = fmaf(wh[0][jj], u.x, a0); a0 = fmaf(wh[0][jj+1], u.y, a0);
                a0 = fmaf(wh[0][jj+2], u.z, a0); a0 = fmaf(wh[0][jj+3], u.w, a0);
                a1 = fmaf(wh[1][jj], u.x, a1); a1 = fmaf(wh[1][jj+1], u.y, a1);
                a1 = fmaf(wh[1][jj+2], u.z, a1); a1 = fmaf(wh[1][jj+3], u.w, a1);
                a2 = fmaf(wh[2][jj], u.x, a2); a2 = fmaf(wh[2][jj+1], u.y, a2);
                a2 = fmaf(wh[2][jj+2], u.z, a2); a2 = fmaf(wh[2][jj+3], u.w, a2);
            }
            a0 += __shfl_xor(a0, 1, 64); a0 += __shfl_xor(a0, 2, 64);
            a1 += __shfl_xor(a1, 1, 64); a1 += __shfl_xor(a1, 2, 64);
            a2 += __shfl_xor(a2, 1, 64); a2 += __shfl_xor(a2, 2, 64);

            if (kt == 0) {   // one lane per quad finalizes hidden unit gt
                float xr, xz, xn;
                if constexpr (FIRST) {
                    const float* xp = &s_in[t * 5];
                    float x0 = xp[0], x1 = xp[1], x2 = xp[2], x3 = xp[3], x4 = xp[4];
                    xr = wx5[0][0]*x0 + wx5[0][1]*x1 + wx5[0][2]*x2 + wx5[0][3]*x3 + wx5[0][4]*x4;
                    xz = wx5[1][0]*x0 + wx5[1][1]*x1 + wx5[1][2]*x2 + wx5[1][3]*x3 + wx5[1][4]*x4;
                    xn = wx5[2][0]*x0 + wx5[2][1]*x1 + wx5[2][2]*x2 + wx5[2][3]*x3 + wx5[2][4]*x4;
                } else {
                    const float* xp = &s_xi[tw * G3];
                    xr = xp[gt]; xz = xp[HH + gt]; xn = xp[2 * HH + gt];
                }
                float r = sigmoidf_(xr + a0 + br);
                float z = sigmoidf_(xz + a1 + bz);
                float n = tanhf_(xn + bxn + r * (a2 + bhn));
                float hp_ = s_h[cur][gt >> 5][gt & 31];
                float hv  = (1.0f - z) * n + z * hp_;
                s_h[cur ^ 1][gt >> 5][gt & 31] = hv;
                if constexpr (!LAST)
                    out[((size_t)b * TT + t) * HH + gt] = hv;
            }
            lds_barrier();   // single per-step barrier (lgkm only)
        }
    }

    if constexpr (LAST) {
        // fused FC: final h in s_h[0] (cur^1 of t=511); one wave reduces
        if (tid < 64) {
            float h0 = s_h[0][tid >> 5][tid & 31];
            float h1 = s_h[0][(tid >> 5) + 2][tid & 31];
            float s = h0 * fcw[tid] + h1 * fcw[tid + 64];
#pragma unroll
            for (int m = 32; m >= 1; m >>= 1) s += __shfl_xor(s, m, 64);
            if (tid == 0) fcout[b] = s + fcb[0];
        }
    }
}

extern "C" void kernel_launch(void* const* d_in, const int* in_sizes, int n_in,
                              void* d_out, int out_size, void* d_ws, size_t ws_size,
                              hipStream_t stream) {
    const float* x    = (const float*)d_in[0];
    const float* Wih0 = (const float*)d_in[1];
    const float* Whh0 = (const float*)d_in[2];
    const float* bih0 = (const float*)d_in[3];
    const float* bhh0 = (const float*)d_in[4];
    const float* WihR = (const float*)d_in[5];
    const float* WhhR = (const float*)d_in[6];
    const float* bihR = (const float*)d_in[7];
    const float* bhhR = (const float*)d_in[8];
    const float* fcw  = (const float*)d_in[9];
    const float* fcb  = (const float*)d_in[10];

    float* buf = (float*)d_ws;   // 512*512*128*4 = 134 MB, in-place across layers

    gru_layer<true, false><<<NBLK, NTHR, 0, stream>>>(x, buf, Wih0, Whh0, bih0, bhh0,
                                                      nullptr, nullptr, nullptr);
    gru_layer<false, false><<<NBLK, NTHR, 0, stream>>>(buf, buf, WihR, WhhR, bihR, bhhR,
                                                       nullptr, nullptr, nullptr);
    gru_layer<false, false><<<NBLK, NTHR, 0, stream>>>(buf, buf, WihR + G3 * HH,
                                                       WhhR + G3 * HH, bihR + G3, bhhR + G3,
                                                       nullptr, nullptr, nullptr);
    gru_layer<false, true><<<NBLK, NTHR, 0, stream>>>(buf, buf, WihR + 2 * G3 * HH,
                                                      WhhR + 2 * G3 * HH, bihR + 2 * G3,
                                                      bhhR + 2 * G3, fcw, fcb, (float*)d_out);
}